// Round 2
// baseline (543.182 us; speedup 1.0000x reference)
//
#include <hip/hip_runtime.h>

// GatedDeltaNet fused kernel for MI355X (gfx950).
// I/O tensors fp32 (per reference dtypes); matmuls internally bf16 via
// mfma_f32_16x16x32_bf16.  B=64, T=4096, D=64.
// Pre-pass kernel converts the six 64x64 weight mats + biases to bf16 in d_ws.
// Main kernel: block = 256 threads (4 waves) per (batch, 32-timestep tile),
// +/-1 halo rows for the depthwise conv3.

#define TBS 32          // time-steps per block (output rows)
#define ROWS 34         // TBS + 2 halo
#define DD 64
#define T_LEN 4096
#define LSTRIDE 72      // bf16 LDS row stride: 144B = 16B-aligned, 2-way bank aliasing (free)

typedef unsigned short ushort_t;
typedef short bf16x8 __attribute__((ext_vector_type(8)));   // 8 bf16 = 4 VGPRs
typedef float f32x4 __attribute__((ext_vector_type(4)));

__device__ inline float b2f(ushort_t u) { return __uint_as_float(((unsigned)u) << 16); }
__device__ inline ushort_t f2b(float f) {
    unsigned u = __float_as_uint(f);
    u += 0x7fffu + ((u >> 16) & 1u);        // round-to-nearest-even
    return (ushort_t)(u >> 16);
}
__device__ inline float wave_sum(float v) {
#pragma unroll
    for (int off = 32; off; off >>= 1) v += __shfl_xor(v, off, 64);
    return v;
}
__device__ inline float sigmoidf_(float x) { return 1.f / (1.f + __expf(-x)); }
__device__ inline float tanhf_(float x) {
    float xc = fminf(fmaxf(x, -15.f), 15.f);
    float e2 = __expf(2.f * xc);
    return (e2 - 1.f) / (e2 + 1.f);
}

// ---- pre-pass: fp32 -> bf16 weight pack into d_ws ---------------------------
// layout (ushort elements): qw 0, kw 4096, vw 8192, aw 12288, bw 16384,
//                           pw 20480, then biases q/k/v/a/b/p at 24576+64*i
__global__ __launch_bounds__(256) void cvt_kernel(
    const float* __restrict__ w0, const float* __restrict__ w1,
    const float* __restrict__ w2, const float* __restrict__ w3,
    const float* __restrict__ w4, const float* __restrict__ w5,
    const float* __restrict__ b0, const float* __restrict__ b1,
    const float* __restrict__ b2, const float* __restrict__ b3,
    const float* __restrict__ b4, const float* __restrict__ b5,
    ushort_t* __restrict__ dst) {
    int i = blockIdx.x * 256 + threadIdx.x;
    if (i >= 24960) return;
    const float* src; int off;
    if (i < 24576) {
        const float* ws_[6] = {w0, w1, w2, w3, w4, w5};
        src = ws_[i >> 12]; off = i & 4095;
    } else {
        int j = i - 24576;
        const float* bs_[6] = {b0, b1, b2, b3, b4, b5};
        src = bs_[j >> 6]; off = j & 63;
    }
    dst[i] = f2b(src[off]);
}

// Y[r][o] = sum_d A[r][d] * W[o][d] + bias[o]
// A: LDS bf16, row stride LSTRIDE. W,bias: bf16 pack (row-major [64][64]).
// Fdst: LDS f32, row stride 64.  Rows covered: m_off + [0, 16*n_mtiles).
__device__ inline void mm_tiles(const ushort_t* __restrict__ Wg,
                                const ushort_t* __restrict__ bg,
                                const ushort_t* Asrc, float* Fdst,
                                int m_off, int n_mtiles, int wave, int lane) {
    const int l15 = lane & 15;
    const int kq  = (lane >> 4) * 8;     // quad * 8
    const int total = n_mtiles * 4;      // 4 n-tiles (N=64)
    for (int tile = wave; tile < total; tile += 4) {
        const int mt = tile >> 2;
        const int nt = tile & 3;
        const int m0 = m_off + mt * 16;
        const int ncol = nt * 16 + l15;
        // A fragment: A[m=lane&15][k=quad*8+j], two K=32 halves
        const bf16x8 a0 = *(const bf16x8*)(Asrc + (m0 + l15) * LSTRIDE + kq);
        const bf16x8 a1 = *(const bf16x8*)(Asrc + (m0 + l15) * LSTRIDE + 32 + kq);
        // B fragment: B[k][n] = W[n][k] -> contiguous 8 bf16 from W row n
        const bf16x8 b0 = *(const bf16x8*)(Wg + ncol * 64 + kq);
        const bf16x8 b1 = *(const bf16x8*)(Wg + ncol * 64 + 32 + kq);
        f32x4 acc = {0.f, 0.f, 0.f, 0.f};
        acc = __builtin_amdgcn_mfma_f32_16x16x32_bf16(a0, b0, acc, 0, 0, 0);
        acc = __builtin_amdgcn_mfma_f32_16x16x32_bf16(a1, b1, acc, 0, 0, 0);
        const float bias = b2f(bg[ncol]);
        const int row0 = m0 + (lane >> 4) * 4;   // C/D: row = quad*4 + i, col = lane&15
#pragma unroll
        for (int i = 0; i < 4; i++)
            Fdst[(row0 + i) * 64 + ncol] = acc[i] + bias;
    }
}

__global__ __launch_bounds__(256) void gdn_kernel(
    const float* __restrict__ xg, const float* __restrict__ norm_g,
    const ushort_t* __restrict__ wpack,
    const float* __restrict__ qcw, const float* __restrict__ qcb,
    const float* __restrict__ kcw, const float* __restrict__ kcb,
    const float* __restrict__ vcw, const float* __restrict__ vcb,
    const float* __restrict__ post_g,
    float* __restrict__ outg, int tiles_per_b) {
    __shared__ __align__(16) ushort_t Xs[ROWS * LSTRIDE];   // bf16 x rows t0-1 .. t0+32
    __shared__ __align__(16) ushort_t Hs[48 * LSTRIDE];     // bf16 zc_rmsnorm(x); rows 34..47 zero
    __shared__ __align__(16) ushort_t Ns[ROWS * LSTRIDE];   // bf16 zc_rmsnorm(delta2)
    __shared__ __align__(16) float Xf[TBS * 64];            // fp32 x rows 1..32 (residual)
    __shared__ __align__(16) float F1[48 * 64];             // linear scratch
    __shared__ __align__(16) float F2[ROWS * 64];           // q -> delta
    __shared__ __align__(16) float F3[ROWS * 64];           // k -> blin

    const int tid  = threadIdx.x;
    const int wave = tid >> 6;
    const int lane = tid & 63;
    const int c    = lane;
    const int bidx = blockIdx.x;
    const int b    = bidx / tiles_per_b;
    const int tile = bidx % tiles_per_b;
    const int t0   = tile * TBS;
    const bool left_edge  = (t0 == 0);
    const bool right_edge = (t0 + TBS >= T_LEN);

    const ushort_t* qw = wpack;
    const ushort_t* kw = wpack + 4096;
    const ushort_t* vw = wpack + 8192;
    const ushort_t* aw = wpack + 12288;
    const ushort_t* bw = wpack + 16384;
    const ushort_t* pw = wpack + 20480;
    const ushort_t* qb = wpack + 24576;
    const ushort_t* kb = wpack + 24640;
    const ushort_t* vb = wpack + 24704;
    const ushort_t* ab = wpack + 24768;
    const ushort_t* bb = wpack + 24832;
    const ushort_t* pb = wpack + 24896;

    // ---- Stage 1: load x tile (+halo); bf16 to Xs, fp32 rows 1..32 to Xf ---
    for (int i = tid; i < ROWS * DD; i += 256) {
        int r = i >> 6, cc = i & 63;
        int t = t0 + r - 1;
        float v = 0.f;
        if (t >= 0 && t < T_LEN) v = xg[((size_t)b * T_LEN + t) * DD + cc];
        Xs[r * LSTRIDE + cc] = f2b(v);
        if (r >= 1 && r <= TBS) Xf[(r - 1) * DD + cc] = v;
    }
    for (int i = tid; i < (48 - ROWS) * LSTRIDE; i += 256) Hs[ROWS * LSTRIDE + i] = 0;
    __syncthreads();

    // ---- Stage 2: h = zc_rmsnorm(x) * g, rows 0..33 (wave-per-row) ---------
    {
        const float g = norm_g[c];
        for (int r = wave; r < ROWS; r += 4) {
            float v = b2f(Xs[r * LSTRIDE + c]);
            float mean = wave_sum(v) * (1.f / 64.f);
            float x0 = v - mean;
            float ms = wave_sum(x0 * x0) * (1.f / 64.f);
            float h = x0 * rsqrtf(ms + 1e-8f) * g;
            Hs[r * LSTRIDE + c] = f2b(h);
        }
    }
    __syncthreads();

    // ---- q ------------------------------------------------------------------
    mm_tiles(qw, qb, Hs, F1, 0, 3, wave, lane);   // qlin rows 0..47 (34+ unused)
    __syncthreads();
    {   // conv3 + sigmoid + l2norm -> F2 rows 1..32
        const float w0 = qcw[c * 3 + 0], w1 = qcw[c * 3 + 1], w2 = qcw[c * 3 + 2];
        const float cb = qcb[c];
        for (int r = 1 + wave; r <= TBS; r += 4) {
            float xm = F1[(r - 1) * 64 + c]; if (r == 1 && left_edge) xm = 0.f;
            float x0 = F1[r * 64 + c];
            float xp = F1[(r + 1) * 64 + c]; if (r == TBS && right_edge) xp = 0.f;
            float s = sigmoidf_(w0 * xm + w1 * x0 + w2 * xp + cb);
            float ss = wave_sum(s * s);
            F2[r * 64 + c] = s * rsqrtf(ss + 1e-8f);
        }
    }
    __syncthreads();

    // ---- k ------------------------------------------------------------------
    mm_tiles(kw, kb, Hs, F1, 0, 3, wave, lane);
    __syncthreads();
    {
        const float w0 = kcw[c * 3 + 0], w1 = kcw[c * 3 + 1], w2 = kcw[c * 3 + 2];
        const float cb = kcb[c];
        for (int r = 1 + wave; r <= TBS; r += 4) {
            float xm = F1[(r - 1) * 64 + c]; if (r == 1 && left_edge) xm = 0.f;
            float x0 = F1[r * 64 + c];
            float xp = F1[(r + 1) * 64 + c]; if (r == TBS && right_edge) xp = 0.f;
            float s = sigmoidf_(w0 * xm + w1 * x0 + w2 * xp + cb);
            float ss = wave_sum(s * s);
            F3[r * 64 + c] = s * rsqrtf(ss + 1e-8f);
        }
    }
    __syncthreads();

    // ---- v + delta = q*(k*v) -----------------------------------------------
    mm_tiles(vw, vb, Hs, F1, 0, 3, wave, lane);
    __syncthreads();
    {
        const float w0 = vcw[c * 3 + 0], w1 = vcw[c * 3 + 1], w2 = vcw[c * 3 + 2];
        const float cb = vcb[c];
        for (int r = 1 + wave; r <= TBS; r += 4) {
            float xm = F1[(r - 1) * 64 + c]; if (r == 1 && left_edge) xm = 0.f;
            float x0 = F1[r * 64 + c];
            float xp = F1[(r + 1) * 64 + c]; if (r == TBS && right_edge) xp = 0.f;
            float v = sigmoidf_(w0 * xm + w1 * x0 + w2 * xp + cb);
            F2[r * 64 + c] = F2[r * 64 + c] * F3[r * 64 + c] * v;   // delta
        }
    }
    __syncthreads();

    // ---- a,b linears on original x (rows 1..32) ----------------------------
    mm_tiles(aw, ab, Xs, F1, 1, 2, wave, lane);   // alin -> F1 rows 1..32
    mm_tiles(bw, bb, Xs, F3, 1, 2, wave, lane);   // blin -> F3 rows 1..32
    __syncthreads();

    // ---- delta2 = tanh(alin)*delta + blin; post zc_rmsnorm -> Ns -----------
    {
        const float pg = post_g[c];
        for (int r = 1 + wave; r <= TBS; r += 4) {
            float d2 = tanhf_(F1[r * 64 + c]) * F2[r * 64 + c] + F3[r * 64 + c];
            float mean = wave_sum(d2) * (1.f / 64.f);
            float x0 = d2 - mean;
            float ms = wave_sum(x0 * x0) * (1.f / 64.f);
            float nd = x0 * rsqrtf(ms + 1e-8f) * pg;
            Ns[r * LSTRIDE + c] = f2b(nd);
        }
    }
    __syncthreads();

    // ---- dhat = Ns @ pw^T + pb ---------------------------------------------
    mm_tiles(pw, pb, Ns, F1, 1, 2, wave, lane);
    __syncthreads();

    // ---- out = x + sigmoid(silu(dhat)) * dhat ------------------------------
    {
        const size_t obase = ((size_t)b * T_LEN + t0) * DD;
        for (int r = 1 + wave; r <= TBS; r += 4) {
            float dh = F1[r * 64 + c];
            float sl = dh * sigmoidf_(dh);                 // silu
            float o = Xf[(r - 1) * 64 + c] + sigmoidf_(sl) * dh;
            outg[obase + (size_t)(r - 1) * DD + c] = o;
        }
    }
}

extern "C" void kernel_launch(void* const* d_in, const int* in_sizes, int n_in,
                              void* d_out, int out_size, void* d_ws, size_t ws_size,
                              hipStream_t stream) {
    const float* xg     = (const float*)d_in[0];
    const float* norm_g = (const float*)d_in[1];
    const float* qw  = (const float*)d_in[2];
    const float* qb  = (const float*)d_in[3];
    const float* kw  = (const float*)d_in[4];
    const float* kb  = (const float*)d_in[5];
    const float* vw  = (const float*)d_in[6];
    const float* vb  = (const float*)d_in[7];
    const float* qcw = (const float*)d_in[8];
    const float* qcb = (const float*)d_in[9];
    const float* kcw = (const float*)d_in[10];
    const float* kcb = (const float*)d_in[11];
    const float* vcw = (const float*)d_in[12];
    const float* vcb = (const float*)d_in[13];
    const float* aw  = (const float*)d_in[14];
    const float* ab  = (const float*)d_in[15];
    const float* bw  = (const float*)d_in[16];
    const float* bb  = (const float*)d_in[17];
    const float* pg  = (const float*)d_in[18];
    const float* pw  = (const float*)d_in[19];
    const float* pb  = (const float*)d_in[20];

    ushort_t* wpack = (ushort_t*)d_ws;

    hipLaunchKernelGGL(cvt_kernel, dim3(98), dim3(256), 0, stream,
                       qw, kw, vw, aw, bw, pw, qb, kb, vb, ab, bb, pb, wpack);

    const int B = in_sizes[0] / (T_LEN * DD);
    const int tiles_per_b = T_LEN / TBS;    // 128
    hipLaunchKernelGGL(gdn_kernel, dim3(B * tiles_per_b), dim3(256), 0, stream,
                       xg, norm_g, wpack, qcw, qcb, kcw, kcb, vcw, vcb, pg,
                       (float*)d_out, tiles_per_b);
}

// Round 3
// 292.419 us; speedup vs baseline: 1.8575x; 1.8575x over previous
//
#include <hip/hip_runtime.h>

// GatedDeltaNet fused kernel for MI355X (gfx950) — R3.
// I/O fp32; matmuls internally bf16 via mfma_f32_16x16x32_bf16.
// B=64, T=4096, D=64.  Block = 256 threads (4 waves) per 32-timestep tile.
// Layout trick: in element-wise stages lane = (row_in_wavegroup<<3)|chgroup,
// so a wave covers 8 rows at once and channel reductions are 3 shuffle hops.
// 6 barriers per block (was 13).  LDS 39.9 KB -> 4 blocks/CU.

#define TBS 32
#define ROWS 34          // TBS + 2 halo
#define DD 64
#define T_LEN 4096
#define LSTRIDE 72       // ushort stride: 144 B = 16B-aligned, 2-way bank alias (free)

typedef unsigned short ushort_t;
typedef short bf16x8 __attribute__((ext_vector_type(8)));   // 8 bf16 = 4 VGPRs
typedef float f32x4 __attribute__((ext_vector_type(4)));

__device__ inline float b2f(ushort_t u) { return __uint_as_float(((unsigned)u) << 16); }
__device__ inline ushort_t f2b(float f) {
    unsigned u = __float_as_uint(f);
    u += 0x7fffu + ((u >> 16) & 1u);        // RNE
    return (ushort_t)(u >> 16);
}
__device__ inline float sum8(float v) {      // reduce over 8-lane group
    v += __shfl_xor(v, 1, 64);
    v += __shfl_xor(v, 2, 64);
    v += __shfl_xor(v, 4, 64);
    return v;
}
__device__ inline float sigmoidf_(float x) { return 1.f / (1.f + __expf(-x)); }
__device__ inline float tanhf_(float x) {
    float xc = fminf(fmaxf(x, -15.f), 15.f);
    float e2 = __expf(2.f * xc);
    return (e2 - 1.f) / (e2 + 1.f);
}

// ---- pre-pass: fp32 -> bf16 weight pack into d_ws ---------------------------
// ushort layout: qw 0, kw 4096, vw 8192, aw 12288, bw 16384, pw 20480,
//                biases q/k/v/a/b/p at 24576 + 64*i
__global__ __launch_bounds__(256) void cvt_kernel(
    const float* __restrict__ w0, const float* __restrict__ w1,
    const float* __restrict__ w2, const float* __restrict__ w3,
    const float* __restrict__ w4, const float* __restrict__ w5,
    const float* __restrict__ b0, const float* __restrict__ b1,
    const float* __restrict__ b2, const float* __restrict__ b3,
    const float* __restrict__ b4, const float* __restrict__ b5,
    ushort_t* __restrict__ dst) {
    int i = blockIdx.x * 256 + threadIdx.x;
    if (i >= 24960) return;
    const float* src; int off;
    if (i < 24576) {
        const float* ws_[6] = {w0, w1, w2, w3, w4, w5};
        src = ws_[i >> 12]; off = i & 4095;
    } else {
        int j = i - 24576;
        const float* bs_[6] = {b0, b1, b2, b3, b4, b5};
        src = bs_[j >> 6]; off = j & 63;
    }
    dst[i] = f2b(src[off]);
}

// Y[r][o] = sum_d A[r][d]*W[o][d] + bias[o]; A,Dst: LDS bf16 stride LSTRIDE.
// W,bias: bf16 pack.  Rows m_off..m_off+16*n_mtiles-1, stores predicated < max_row.
__device__ inline void mm_bf16(const ushort_t* __restrict__ Wg,
                               const ushort_t* __restrict__ bg,
                               const ushort_t* Asrc, ushort_t* Dst,
                               int m_off, int n_mtiles, int max_row,
                               int wave, int lane) {
    const int l15 = lane & 15;
    const int kq  = (lane >> 4) * 8;
    const int total = n_mtiles * 4;
    for (int tile = wave; tile < total; tile += 4) {
        const int mt = tile >> 2;
        const int nt = tile & 3;
        const int m0 = m_off + mt * 16;
        const int ncol = nt * 16 + l15;
        const bf16x8 a0 = *(const bf16x8*)(Asrc + (m0 + l15) * LSTRIDE + kq);
        const bf16x8 a1 = *(const bf16x8*)(Asrc + (m0 + l15) * LSTRIDE + 32 + kq);
        const bf16x8 b0 = *(const bf16x8*)(Wg + ncol * 64 + kq);
        const bf16x8 b1 = *(const bf16x8*)(Wg + ncol * 64 + 32 + kq);
        f32x4 acc = {0.f, 0.f, 0.f, 0.f};
        acc = __builtin_amdgcn_mfma_f32_16x16x32_bf16(a0, b0, acc, 0, 0, 0);
        acc = __builtin_amdgcn_mfma_f32_16x16x32_bf16(a1, b1, acc, 0, 0, 0);
        const float bias = b2f(bg[ncol]);
        const int row0 = m0 + (lane >> 4) * 4;
#pragma unroll
        for (int i = 0; i < 4; i++) {
            int row = row0 + i;
            if (row < max_row) Dst[row * LSTRIDE + ncol] = f2b(acc[i] + bias);
        }
    }
}

// conv3 (zero-pad) + sigmoid on 8 channels of row rr from bf16 buffer F.
// CW: tap-major [3][64] fp32 in LDS; CB: bias[64].
__device__ inline void conv_sig8(const float* __restrict__ CW,
                                 const float* __restrict__ CB, int cb,
                                 const ushort_t* F, int rr, bool zl, bool zr,
                                 float out[8]) {
    bf16x8 m_ = *(const bf16x8*)(F + (rr - 1) * LSTRIDE + cb);
    bf16x8 c_ = *(const bf16x8*)(F + rr * LSTRIDE + cb);
    bf16x8 p_ = *(const bf16x8*)(F + (rr + 1) * LSTRIDE + cb);
#pragma unroll
    for (int i = 0; i < 8; i++) {
        float xm = zl ? 0.f : b2f((ushort_t)m_[i]);
        float x0 = b2f((ushort_t)c_[i]);
        float xp = zr ? 0.f : b2f((ushort_t)p_[i]);
        float a = fmaf(CW[cb + i], xm,
                  fmaf(CW[64 + cb + i], x0,
                  fmaf(CW[128 + cb + i], xp, CB[cb + i])));
        out[i] = sigmoidf_(a);
    }
}

__global__ __launch_bounds__(256, 4) void gdn_kernel(
    const float* __restrict__ xg, const float* __restrict__ norm_g,
    const ushort_t* __restrict__ wpack,
    const float* __restrict__ qcw, const float* __restrict__ qcb,
    const float* __restrict__ kcw, const float* __restrict__ kcb,
    const float* __restrict__ vcw, const float* __restrict__ vcb,
    const float* __restrict__ post_g,
    float* __restrict__ outg, int tiles_per_b) {
    __shared__ __align__(16) ushort_t Xs[ROWS * LSTRIDE];   // bf16 x rows t0-1..t0+32
    __shared__ __align__(16) ushort_t Hs[48 * LSTRIDE];     // h; later Ns; rows 34..47 zero
    __shared__ __align__(16) ushort_t Fq[ROWS * LSTRIDE];   // qlin; later dhat
    __shared__ __align__(16) ushort_t Fk[ROWS * LSTRIDE];
    __shared__ __align__(16) ushort_t Fv[ROWS * LSTRIDE];
    __shared__ __align__(16) ushort_t Fa[ROWS * LSTRIDE];
    __shared__ __align__(16) ushort_t Fb[ROWS * LSTRIDE];
    __shared__ __align__(16) float CWs[896];
    // CWs: [0..191] q taps (tap-major [3][64]); [192..383] k; [384..575] v;
    //      [576] qcb; [640] kcb; [704] vcb; [768] norm_g; [832] post_g

    const int tid  = threadIdx.x;
    const int wave = tid >> 6;
    const int lane = tid & 63;
    const int g8   = lane & 7;          // channel group
    const int cb   = g8 * 8;            // channel base
    const int rw   = lane >> 3;         // row-in-wavegroup 0..7
    const int bidx = blockIdx.x;
    const int b    = bidx / tiles_per_b;
    const int tile = bidx % tiles_per_b;
    const int t0   = tile * TBS;
    const bool left_edge  = (t0 == 0);
    const bool right_edge = (t0 + TBS >= T_LEN);

    const ushort_t* qw = wpack;
    const ushort_t* kw = wpack + 4096;
    const ushort_t* vw = wpack + 8192;
    const ushort_t* aw = wpack + 12288;
    const ushort_t* bw = wpack + 16384;
    const ushort_t* pw = wpack + 20480;
    const ushort_t* qb = wpack + 24576;
    const ushort_t* kb = wpack + 24640;
    const ushort_t* vb = wpack + 24704;
    const ushort_t* ab = wpack + 24768;
    const ushort_t* bb = wpack + 24832;
    const ushort_t* pb = wpack + 24896;

    // ---- Stage 1: x tile -> Xs (bf16); conv weights/gains -> CWs; zero Hs pad
    for (int i = tid; i < ROWS * 16; i += 256) {        // 544 float4s
        int r = i >> 4, c4 = (i & 15) * 4;
        int t = t0 + r - 1;
        f32x4 v = {0.f, 0.f, 0.f, 0.f};
        if (t >= 0 && t < T_LEN)
            v = *(const f32x4*)(xg + ((size_t)b * T_LEN + t) * DD + c4);
        ushort4 pk;
        pk.x = f2b(v[0]); pk.y = f2b(v[1]); pk.z = f2b(v[2]); pk.w = f2b(v[3]);
        *(ushort4*)(Xs + r * LSTRIDE + c4) = pk;
    }
    if (tid < 192) {
        int tap = tid >> 6, c = tid & 63;
        CWs[tid]       = qcw[c * 3 + tap];
        CWs[192 + tid] = kcw[c * 3 + tap];
        CWs[384 + tid] = vcw[c * 3 + tap];
    } else {
        int c = tid - 192;
        CWs[576 + c] = qcb[c];
        CWs[640 + c] = kcb[c];
        CWs[704 + c] = vcb[c];
        CWs[768 + c] = norm_g[c];
        CWs[832 + c] = post_g[c];
    }
    {
        unsigned* hz = (unsigned*)(Hs + ROWS * LSTRIDE);    // rows 34..47
        for (int i = tid; i < (48 - ROWS) * LSTRIDE / 2; i += 256) hz[i] = 0;
    }
    __syncthreads();

    // ---- Stage 2: h = zc_rmsnorm(x)*g, rows 0..33 ---------------------------
    for (int rb = 0; rb < ROWS; rb += 32) {
        int r = rb + wave * 8 + rw;
        if (r < ROWS) {
            bf16x8 xv = *(const bf16x8*)(Xs + r * LSTRIDE + cb);
            float xf[8]; float s = 0.f;
#pragma unroll
            for (int i = 0; i < 8; i++) { xf[i] = b2f((ushort_t)xv[i]); s += xf[i]; }
            float mean = sum8(s) * (1.f / 64.f);
            float ms = 0.f;
#pragma unroll
            for (int i = 0; i < 8; i++) { xf[i] -= mean; ms = fmaf(xf[i], xf[i], ms); }
            float inv = rsqrtf(sum8(ms) * (1.f / 64.f) + 1e-8f);
            bf16x8 hv;
#pragma unroll
            for (int i = 0; i < 8; i++) hv[i] = (short)f2b(xf[i] * inv * CWs[768 + cb + i]);
            *(bf16x8*)(Hs + r * LSTRIDE + cb) = hv;
        }
    }
    __syncthreads();

    // ---- Stage 3: five linears, one barrier pair ---------------------------
    mm_bf16(qw, qb, Hs, Fq, 0, 3, ROWS, wave, lane);    // rows 0..33
    mm_bf16(kw, kb, Hs, Fk, 0, 3, ROWS, wave, lane);
    mm_bf16(vw, vb, Hs, Fv, 0, 3, ROWS, wave, lane);
    mm_bf16(aw, ab, Xs, Fa, 1, 2, ROWS, wave, lane);    // rows 1..32
    mm_bf16(bw, bb, Xs, Fb, 1, 2, ROWS, wave, lane);
    __syncthreads();

    // ---- Stage 4: conv+sig (q,k,v), l2norm(q,k), delta, gate, post-norm ----
    {
        const int rr = wave * 8 + rw + 1;               // 1..32
        const bool zl = (rr == 1) && left_edge;
        const bool zr = (rr == TBS) && right_edge;
        float qs[8], ks[8], vs[8];
        conv_sig8(CWs,        CWs + 576, cb, Fq, rr, zl, zr, qs);
        conv_sig8(CWs + 192,  CWs + 640, cb, Fk, rr, zl, zr, ks);
        conv_sig8(CWs + 384,  CWs + 704, cb, Fv, rr, zl, zr, vs);
        float sq = 0.f, sk = 0.f;
#pragma unroll
        for (int i = 0; i < 8; i++) {
            sq = fmaf(qs[i], qs[i], sq);
            sk = fmaf(ks[i], ks[i], sk);
        }
        float qi = rsqrtf(sum8(sq) + 1e-8f);
        float ki = rsqrtf(sum8(sk) + 1e-8f);
        bf16x8 av = *(const bf16x8*)(Fa + rr * LSTRIDE + cb);
        bf16x8 bv = *(const bf16x8*)(Fb + rr * LSTRIDE + cb);
        float d2[8]; float sm = 0.f;
#pragma unroll
        for (int i = 0; i < 8; i++) {
            float delta = (qs[i] * qi) * (ks[i] * ki) * vs[i];
            d2[i] = fmaf(tanhf_(b2f((ushort_t)av[i])), delta, b2f((ushort_t)bv[i]));
            sm += d2[i];
        }
        float mean = sum8(sm) * (1.f / 64.f);
        float ms = 0.f;
#pragma unroll
        for (int i = 0; i < 8; i++) { d2[i] -= mean; ms = fmaf(d2[i], d2[i], ms); }
        float inv = rsqrtf(sum8(ms) * (1.f / 64.f) + 1e-8f);
        bf16x8 nv;
#pragma unroll
        for (int i = 0; i < 8; i++) nv[i] = (short)f2b(d2[i] * inv * CWs[832 + cb + i]);
        *(bf16x8*)(Hs + rr * LSTRIDE + cb) = nv;        // Ns into Hs rows 1..32
    }
    __syncthreads();

    // ---- Stage 5: dhat = Ns @ pw^T + pb -> Fq rows 1..32 -------------------
    mm_bf16(pw, pb, Hs, Fq, 1, 2, ROWS, wave, lane);
    __syncthreads();

    // ---- Stage 6: out = x + sigmoid(silu(dhat))*dhat -----------------------
    {
        const int rr = wave * 8 + rw + 1;               // 1..32
        const int t = t0 + rr - 1;
        bf16x8 dh8 = *(const bf16x8*)(Fq + rr * LSTRIDE + cb);
        const float* xrow = xg + ((size_t)b * T_LEN + t) * DD + cb;
        float* orow = outg + ((size_t)b * T_LEN + t) * DD + cb;
        f32x4 x0 = *(const f32x4*)(xrow);
        f32x4 x1 = *(const f32x4*)(xrow + 4);
        f32x4 o0, o1;
#pragma unroll
        for (int i = 0; i < 4; i++) {
            float dh = b2f((ushort_t)dh8[i]);
            float sl = dh * sigmoidf_(dh);
            o0[i] = x0[i] + sigmoidf_(sl) * dh;
        }
#pragma unroll
        for (int i = 0; i < 4; i++) {
            float dh = b2f((ushort_t)dh8[4 + i]);
            float sl = dh * sigmoidf_(dh);
            o1[i] = x1[i] + sigmoidf_(sl) * dh;
        }
        *(f32x4*)(orow) = o0;
        *(f32x4*)(orow + 4) = o1;
    }
}

extern "C" void kernel_launch(void* const* d_in, const int* in_sizes, int n_in,
                              void* d_out, int out_size, void* d_ws, size_t ws_size,
                              hipStream_t stream) {
    const float* xg     = (const float*)d_in[0];
    const float* norm_g = (const float*)d_in[1];
    const float* qw  = (const float*)d_in[2];
    const float* qb  = (const float*)d_in[3];
    const float* kw  = (const float*)d_in[4];
    const float* kb  = (const float*)d_in[5];
    const float* vw  = (const float*)d_in[6];
    const float* vb  = (const float*)d_in[7];
    const float* qcw = (const float*)d_in[8];
    const float* qcb = (const float*)d_in[9];
    const float* kcw = (const float*)d_in[10];
    const float* kcb = (const float*)d_in[11];
    const float* vcw = (const float*)d_in[12];
    const float* vcb = (const float*)d_in[13];
    const float* aw  = (const float*)d_in[14];
    const float* ab  = (const float*)d_in[15];
    const float* bw  = (const float*)d_in[16];
    const float* bb  = (const float*)d_in[17];
    const float* pg  = (const float*)d_in[18];
    const float* pw  = (const float*)d_in[19];
    const float* pb  = (const float*)d_in[20];

    ushort_t* wpack = (ushort_t*)d_ws;

    hipLaunchKernelGGL(cvt_kernel, dim3(98), dim3(256), 0, stream,
                       qw, kw, vw, aw, bw, pw, qb, kb, vb, ab, bb, pb, wpack);

    const int B = in_sizes[0] / (T_LEN * DD);
    const int tiles_per_b = T_LEN / TBS;    // 128
    hipLaunchKernelGGL(gdn_kernel, dim3(B * tiles_per_b), dim3(256), 0, stream,
                       xg, norm_g, wpack, qcw, qcb, kcw, kcb, vcw, vcb, pg,
                       (float*)d_out, tiles_per_b);
}

// Round 4
// 283.221 us; speedup vs baseline: 1.9179x; 1.0325x over previous
//
#include <hip/hip_runtime.h>

// GatedDeltaNet fused kernel for MI355X (gfx950) — R4.
// I/O fp32; matmuls internally bf16 via mfma_f32_16x16x32_bf16.
// B=64, T=4096, D=64.  Block = 512 threads (8 waves) per 32-timestep tile.
// Element-wise stages: lane16 = tid&15 -> 4 channels/lane, 16-lane reductions
// (4 shuffle hops); 32 rows covered by 512 threads in one pass.
// GEMMs: transposed MFMA (W as A-operand) -> lane's 4 accs = 4 consecutive
// channels of one time row -> single 8B packed LDS store per tile.
// LDS 37.9 KB -> 4 blocks/CU x 8 waves = 32 waves/CU (100% occupancy).

#define TBS 32
#define ROWS 34          // TBS + 2 halo
#define DD 64
#define T_LEN 4096
#define LSTRIDE 72       // ushort stride: 144 B = 16B-aligned, 2-way bank alias (free)

typedef unsigned short ushort_t;
typedef short bf16x8 __attribute__((ext_vector_type(8)));
typedef short bf16x4 __attribute__((ext_vector_type(4)));
typedef float f32x4 __attribute__((ext_vector_type(4)));

__device__ inline float b2f(ushort_t u) { return __uint_as_float(((unsigned)u) << 16); }
__device__ inline ushort_t f2b(float f) {
    unsigned u = __float_as_uint(f);
    u += 0x7fffu + ((u >> 16) & 1u);        // RNE
    return (ushort_t)(u >> 16);
}
__device__ inline float sum16(float v) {     // reduce over 16-lane group
    v += __shfl_xor(v, 1, 64);
    v += __shfl_xor(v, 2, 64);
    v += __shfl_xor(v, 4, 64);
    v += __shfl_xor(v, 8, 64);
    return v;
}
__device__ inline float sigmoidf_(float x) { return 1.f / (1.f + __expf(-x)); }
__device__ inline float tanhf_(float x) {
    float xc = fminf(fmaxf(x, -15.f), 15.f);
    float e2 = __expf(2.f * xc);
    return (e2 - 1.f) / (e2 + 1.f);
}

// ---- pre-pass: fp32 -> bf16 weight pack into d_ws ---------------------------
// ushort layout: qw 0, kw 4096, vw 8192, aw 12288, bw 16384, pw 20480,
//                biases q/k/v/a/b/p at 24576 + 64*i
__global__ __launch_bounds__(256) void cvt_kernel(
    const float* __restrict__ w0, const float* __restrict__ w1,
    const float* __restrict__ w2, const float* __restrict__ w3,
    const float* __restrict__ w4, const float* __restrict__ w5,
    const float* __restrict__ b0, const float* __restrict__ b1,
    const float* __restrict__ b2, const float* __restrict__ b3,
    const float* __restrict__ b4, const float* __restrict__ b5,
    ushort_t* __restrict__ dst) {
    int i = blockIdx.x * 256 + threadIdx.x;
    if (i >= 24960) return;
    const float* src; int off;
    if (i < 24576) {
        const float* ws_[6] = {w0, w1, w2, w3, w4, w5};
        src = ws_[i >> 12]; off = i & 4095;
    } else {
        int j = i - 24576;
        const float* bs_[6] = {b0, b1, b2, b3, b4, b5};
        src = bs_[j >> 6]; off = j & 63;
    }
    dst[i] = f2b(src[off]);
}

// Transposed GEMM tile: D[o][t] = sum_k W[o][k]*A[t][k] + bias[o].
// W as A-operand, activations as B-operand.  C/D: col(l15)=time, row(quad)=o.
// Store: 4 consecutive channels of one time row -> packed 8B write.
// m0_mode 0: time-tiles {0,16,18} (rows 0..33, tail overlap, nmt=3)
// m0_mode 1: time-tiles {1,17}    (rows 1..32, nmt=2)
__device__ inline void mm_t(const ushort_t* __restrict__ Wg,
                            const ushort_t* __restrict__ bg,
                            const ushort_t* Asrc, ushort_t* Dst,
                            int nmt, int m0_mode, int wave, int lane) {
    const int l15  = lane & 15;
    const int quad = lane >> 4;
    const int kq   = quad * 8;
    const int total = nmt * 4;
    for (int tile = wave; tile < total; tile += 8) {
        const int mt = tile >> 2;
        const int nt = tile & 3;
        const int m0 = m0_mode ? (mt * 16 + 1) : min(mt * 16, 18);
        const int ocol = nt * 16 + l15;
        const int o0q  = nt * 16 + quad * 4;
        const int r = m0 + l15;
        const bf16x8 w0 = *(const bf16x8*)(Wg + ocol * 64 + kq);
        const bf16x8 w1 = *(const bf16x8*)(Wg + ocol * 64 + 32 + kq);
        const bf16x8 a0 = *(const bf16x8*)(Asrc + r * LSTRIDE + kq);
        const bf16x8 a1 = *(const bf16x8*)(Asrc + r * LSTRIDE + 32 + kq);
        f32x4 acc = {0.f, 0.f, 0.f, 0.f};
        acc = __builtin_amdgcn_mfma_f32_16x16x32_bf16(w0, a0, acc, 0, 0, 0);
        acc = __builtin_amdgcn_mfma_f32_16x16x32_bf16(w1, a1, acc, 0, 0, 0);
        bf16x4 pk;
#pragma unroll
        for (int i = 0; i < 4; i++)
            pk[i] = (short)f2b(acc[i] + b2f(bg[o0q + i]));
        *(bf16x4*)(Dst + r * LSTRIDE + o0q) = pk;
    }
}

// conv3 (zero-pad) + sigmoid on 4 channels of row rr from bf16 buffer F.
__device__ inline void conv_sig4(const float* __restrict__ CW,
                                 const float* __restrict__ CB, int cb,
                                 const ushort_t* F, int rr, bool zl, bool zr,
                                 float out[4]) {
    bf16x4 m_ = *(const bf16x4*)(F + (rr - 1) * LSTRIDE + cb);
    bf16x4 c_ = *(const bf16x4*)(F + rr * LSTRIDE + cb);
    bf16x4 p_ = *(const bf16x4*)(F + (rr + 1) * LSTRIDE + cb);
    f32x4 w0 = *(const f32x4*)(CW + cb);
    f32x4 w1 = *(const f32x4*)(CW + 64 + cb);
    f32x4 w2 = *(const f32x4*)(CW + 128 + cb);
    f32x4 bb = *(const f32x4*)(CB + cb);
#pragma unroll
    for (int i = 0; i < 4; i++) {
        float xm = zl ? 0.f : b2f((ushort_t)m_[i]);
        float x0 = b2f((ushort_t)c_[i]);
        float xp = zr ? 0.f : b2f((ushort_t)p_[i]);
        float a = fmaf(w0[i], xm, fmaf(w1[i], x0, fmaf(w2[i], xp, bb[i])));
        out[i] = sigmoidf_(a);
    }
}

__global__ __launch_bounds__(512, 8) void gdn_kernel(
    const float* __restrict__ xg, const float* __restrict__ norm_g,
    const ushort_t* __restrict__ wpack,
    const float* __restrict__ qcw, const float* __restrict__ qcb,
    const float* __restrict__ kcw, const float* __restrict__ kcb,
    const float* __restrict__ vcw, const float* __restrict__ vcb,
    const float* __restrict__ post_g,
    float* __restrict__ outg, int tiles_per_b) {
    __shared__ __align__(16) ushort_t Xs[ROWS * LSTRIDE];   // bf16 x rows t0-1..t0+32
    __shared__ __align__(16) ushort_t Hs[ROWS * LSTRIDE];   // h; later Ns
    __shared__ __align__(16) ushort_t Fq[ROWS * LSTRIDE];   // qlin; later dhat
    __shared__ __align__(16) ushort_t Fk[ROWS * LSTRIDE];
    __shared__ __align__(16) ushort_t Fv[ROWS * LSTRIDE];
    __shared__ __align__(16) ushort_t Fa[ROWS * LSTRIDE];
    __shared__ __align__(16) ushort_t Fb[ROWS * LSTRIDE];
    __shared__ __align__(16) float CWs[896];
    // CWs: [0..191] q taps (tap-major [3][64]); [192..383] k; [384..575] v;
    //      [576] qcb; [640] kcb; [704] vcb; [768] norm_g; [832] post_g

    const int tid    = threadIdx.x;
    const int wave   = tid >> 6;
    const int lane   = tid & 63;
    const int lane16 = tid & 15;
    const int cb     = lane16 * 4;      // channel base (4 ch/lane)
    const int rgrp   = tid >> 4;        // 0..31
    const int bidx = blockIdx.x;
    const int b    = bidx / tiles_per_b;
    const int tile = bidx % tiles_per_b;
    const int t0   = tile * TBS;
    const bool left_edge  = (t0 == 0);
    const bool right_edge = (t0 + TBS >= T_LEN);

    const ushort_t* qw = wpack;
    const ushort_t* kw = wpack + 4096;
    const ushort_t* vw = wpack + 8192;
    const ushort_t* aw = wpack + 12288;
    const ushort_t* bw = wpack + 16384;
    const ushort_t* pw = wpack + 20480;
    const ushort_t* qb = wpack + 24576;
    const ushort_t* kb = wpack + 24640;
    const ushort_t* vb = wpack + 24704;
    const ushort_t* ab = wpack + 24768;
    const ushort_t* bb = wpack + 24832;
    const ushort_t* pb = wpack + 24896;

    // ---- Stage 1: x tile -> Xs (bf16); conv weights/gains -> CWs -----------
    for (int i = tid; i < ROWS * 16; i += 512) {        // 544 float4s
        int r = i >> 4, c4 = (i & 15) * 4;
        int t = t0 + r - 1;
        f32x4 v = {0.f, 0.f, 0.f, 0.f};
        if (t >= 0 && t < T_LEN)
            v = *(const f32x4*)(xg + ((size_t)b * T_LEN + t) * DD + c4);
        bf16x4 pk;
#pragma unroll
        for (int j = 0; j < 4; j++) pk[j] = (short)f2b(v[j]);
        *(bf16x4*)(Xs + r * LSTRIDE + c4) = pk;
    }
    if (tid < 192) {
        int tap = tid >> 6, c = tid & 63;
        CWs[tid]       = qcw[c * 3 + tap];
        CWs[192 + tid] = kcw[c * 3 + tap];
        CWs[384 + tid] = vcw[c * 3 + tap];
    } else if (tid < 256) {
        int c = tid - 192;
        CWs[576 + c] = qcb[c];
        CWs[640 + c] = kcb[c];
        CWs[704 + c] = vcb[c];
        CWs[768 + c] = norm_g[c];
        CWs[832 + c] = post_g[c];
    }
    __syncthreads();

    // ---- Stage 2: h = zc_rmsnorm(x)*g, rows 0..33 ---------------------------
    {
        f32x4 gv = *(const f32x4*)(CWs + 768 + cb);
        for (int r = rgrp; r < ROWS; r += 32) {
            bf16x4 xv = *(const bf16x4*)(Xs + r * LSTRIDE + cb);
            float xf[4]; float s = 0.f;
#pragma unroll
            for (int i = 0; i < 4; i++) { xf[i] = b2f((ushort_t)xv[i]); s += xf[i]; }
            float mean = sum16(s) * (1.f / 64.f);
            float ms = 0.f;
#pragma unroll
            for (int i = 0; i < 4; i++) { xf[i] -= mean; ms = fmaf(xf[i], xf[i], ms); }
            float inv = rsqrtf(sum16(ms) * (1.f / 64.f) + 1e-8f);
            bf16x4 hv;
#pragma unroll
            for (int i = 0; i < 4; i++) hv[i] = (short)f2b(xf[i] * inv * gv[i]);
            *(bf16x4*)(Hs + r * LSTRIDE + cb) = hv;
        }
    }
    __syncthreads();

    // ---- Stage 3: five linears, one barrier pair ---------------------------
    mm_t(qw, qb, Hs, Fq, 3, 0, wave, lane);     // rows 0..33
    mm_t(kw, kb, Hs, Fk, 3, 0, wave, lane);
    mm_t(vw, vb, Hs, Fv, 3, 0, wave, lane);
    mm_t(aw, ab, Xs, Fa, 2, 1, wave, lane);     // rows 1..32
    mm_t(bw, bb, Xs, Fb, 2, 1, wave, lane);
    __syncthreads();

    // ---- Stage 4: conv+sig (q,k,v), l2norm(q,k), delta, gate, post-norm ----
    {
        const int rr = rgrp + 1;                // 1..32
        const bool zl = (rr == 1) && left_edge;
        const bool zr = (rr == TBS) && right_edge;
        float qs[4], ks[4], vs[4];
        conv_sig4(CWs,       CWs + 576, cb, Fq, rr, zl, zr, qs);
        conv_sig4(CWs + 192, CWs + 640, cb, Fk, rr, zl, zr, ks);
        conv_sig4(CWs + 384, CWs + 704, cb, Fv, rr, zl, zr, vs);
        float sq = 0.f, sk = 0.f;
#pragma unroll
        for (int i = 0; i < 4; i++) {
            sq = fmaf(qs[i], qs[i], sq);
            sk = fmaf(ks[i], ks[i], sk);
        }
        float qi = rsqrtf(sum16(sq) + 1e-8f);
        float ki = rsqrtf(sum16(sk) + 1e-8f);
        bf16x4 av = *(const bf16x4*)(Fa + rr * LSTRIDE + cb);
        bf16x4 bv = *(const bf16x4*)(Fb + rr * LSTRIDE + cb);
        float d2[4]; float sm = 0.f;
#pragma unroll
        for (int i = 0; i < 4; i++) {
            float delta = (qs[i] * qi) * (ks[i] * ki) * vs[i];
            d2[i] = fmaf(tanhf_(b2f((ushort_t)av[i])), delta, b2f((ushort_t)bv[i]));
            sm += d2[i];
        }
        float mean = sum16(sm) * (1.f / 64.f);
        float ms = 0.f;
#pragma unroll
        for (int i = 0; i < 4; i++) { d2[i] -= mean; ms = fmaf(d2[i], d2[i], ms); }
        float inv = rsqrtf(sum16(ms) * (1.f / 64.f) + 1e-8f);
        f32x4 pgv = *(const f32x4*)(CWs + 832 + cb);
        bf16x4 nv;
#pragma unroll
        for (int i = 0; i < 4; i++) nv[i] = (short)f2b(d2[i] * inv * pgv[i]);
        *(bf16x4*)(Hs + rr * LSTRIDE + cb) = nv;    // Ns into Hs rows 1..32
    }
    __syncthreads();

    // ---- Stage 5: dhat = Ns @ pw^T + pb -> Fq rows 1..32 -------------------
    mm_t(pw, pb, Hs, Fq, 2, 1, wave, lane);
    __syncthreads();

    // ---- Stage 6: out = x + sigmoid(silu(dhat))*dhat -----------------------
    {
        const int rr = rgrp + 1;                // 1..32
        const int t = t0 + rr - 1;
        bf16x4 dh4 = *(const bf16x4*)(Fq + rr * LSTRIDE + cb);
        const float* xrow = xg + ((size_t)b * T_LEN + t) * DD + cb;
        float* orow = outg + ((size_t)b * T_LEN + t) * DD + cb;
        f32x4 xv = *(const f32x4*)(xrow);
        f32x4 ov;
#pragma unroll
        for (int i = 0; i < 4; i++) {
            float dh = b2f((ushort_t)dh4[i]);
            float sl = dh * sigmoidf_(dh);
            ov[i] = xv[i] + sigmoidf_(sl) * dh;
        }
        *(f32x4*)(orow) = ov;
    }
}

extern "C" void kernel_launch(void* const* d_in, const int* in_sizes, int n_in,
                              void* d_out, int out_size, void* d_ws, size_t ws_size,
                              hipStream_t stream) {
    const float* xg     = (const float*)d_in[0];
    const float* norm_g = (const float*)d_in[1];
    const float* qw  = (const float*)d_in[2];
    const float* qb  = (const float*)d_in[3];
    const float* kw  = (const float*)d_in[4];
    const float* kb  = (const float*)d_in[5];
    const float* vw  = (const float*)d_in[6];
    const float* vb  = (const float*)d_in[7];
    const float* qcw = (const float*)d_in[8];
    const float* qcb = (const float*)d_in[9];
    const float* kcw = (const float*)d_in[10];
    const float* kcb = (const float*)d_in[11];
    const float* vcw = (const float*)d_in[12];
    const float* vcb = (const float*)d_in[13];
    const float* aw  = (const float*)d_in[14];
    const float* ab  = (const float*)d_in[15];
    const float* bw  = (const float*)d_in[16];
    const float* bb  = (const float*)d_in[17];
    const float* pg  = (const float*)d_in[18];
    const float* pw  = (const float*)d_in[19];
    const float* pb  = (const float*)d_in[20];

    ushort_t* wpack = (ushort_t*)d_ws;

    hipLaunchKernelGGL(cvt_kernel, dim3(98), dim3(256), 0, stream,
                       qw, kw, vw, aw, bw, pw, qb, kb, vb, ab, bb, pb, wpack);

    const int B = in_sizes[0] / (T_LEN * DD);
    const int tiles_per_b = T_LEN / TBS;    // 128
    hipLaunchKernelGGL(gdn_kernel, dim3(B * tiles_per_b), dim3(512), 0, stream,
                       xg, norm_g, wpack, qcw, qcb, kcw, kcb, vcw, vcb, pg,
                       (float*)d_out, tiles_per_b);
}

// Round 5
// 251.608 us; speedup vs baseline: 2.1588x; 1.1256x over previous
//
#include <hip/hip_runtime.h>

// GatedDeltaNet fused kernel for MI355X (gfx950) — R5.
// I/O fp32; matmuls bf16 via mfma_f32_32x32x16_bf16 (one 32x32 strip-unit per
// wave, 16 units over 8 waves).  bf16 packing via HW v_cvt_pk_bf16_f32.
// Block = 512 threads / 32-timestep tile; x loaded straight from global for
// the norm (no staging round-trip).  4 barriers (was 6).  LDS 37.3 KB.

#define TBS 32
#define ROWS 34          // TBS + 2 halo
#define DD 64
#define T_LEN 4096
#define LSTRIDE 72       // ushort stride: 144 B = 16B-aligned, 2-way bank alias (free)

typedef unsigned short ushort_t;
typedef short bf16x8 __attribute__((ext_vector_type(8)));
typedef float f32x4 __attribute__((ext_vector_type(4)));
typedef float f32x16 __attribute__((ext_vector_type(16)));

__device__ inline float lo2f(unsigned u) { return __uint_as_float(u << 16); }
__device__ inline float hi2f(unsigned u) { return __uint_as_float(u & 0xffff0000u); }
__device__ inline unsigned pk2(float a, float b) {    // bf16(a) in lo16, bf16(b) in hi16, RNE
    unsigned r;
    asm("v_cvt_pk_bf16_f32 %0, %1, %2" : "=v"(r) : "v"(a), "v"(b));
    return r;
}
__device__ inline ushort_t f2b(float f) {             // scalar RNE (cvt_kernel only)
    unsigned u = __float_as_uint(f);
    u += 0x7fffu + ((u >> 16) & 1u);
    return (ushort_t)(u >> 16);
}
__device__ inline float sum16(float v) {
    v += __shfl_xor(v, 1, 64);
    v += __shfl_xor(v, 2, 64);
    v += __shfl_xor(v, 4, 64);
    v += __shfl_xor(v, 8, 64);
    return v;
}
__device__ inline float sigmoidf_(float x) { return 1.f / (1.f + __expf(-x)); }
__device__ inline float tanhf_(float x) {
    float xc = fminf(fmaxf(x, -15.f), 15.f);
    float e2 = __expf(2.f * xc);
    return (e2 - 1.f) / (e2 + 1.f);
}

// ---- pre-pass: fp32 -> bf16 pack of the six 64x64 weight matrices ----------
// ushort layout: qw 0, kw 4096, vw 8192, aw 12288, bw 16384, pw 20480
__global__ __launch_bounds__(256) void cvt_kernel(
    const float* __restrict__ w0, const float* __restrict__ w1,
    const float* __restrict__ w2, const float* __restrict__ w3,
    const float* __restrict__ w4, const float* __restrict__ w5,
    ushort_t* __restrict__ dst) {
    int i = blockIdx.x * 256 + threadIdx.x;            // < 24576
    const float* ws_[6] = {w0, w1, w2, w3, w4, w5};
    dst[i] = f2b(ws_[i >> 12][i & 4095]);
}

// One 32x32 GEMM strip: D[o][t] = sum_k W[o][k]*act[t][k] + bias[o]
// o in [strip*32, strip*32+32), t in [m0, m0+32).
// A-frag (W): m=lane&31 -> o, k=(lane>>5)*8+j.  B-frag (act): n=lane&31 -> t.
// C/D: col(lane&31)=t, row=(reg&3)+8*(reg>>2)+4*(lane>>5) -> o.
__device__ inline void mm32(const ushort_t* __restrict__ W,
                            const float* __restrict__ bias,
                            const ushort_t* src, ushort_t* dst,
                            int m0, int strip, int lane) {
    const int l31  = lane & 31;
    const int half = lane >> 5;
    const int t    = m0 + l31;
    const ushort_t* wrow = W + (strip * 32 + l31) * 64 + half * 8;
    const ushort_t* arow = src + t * LSTRIDE + half * 8;
    f32x16 acc = {};
#pragma unroll
    for (int kk = 0; kk < 4; kk++) {
        bf16x8 af = *(const bf16x8*)(wrow + kk * 16);
        bf16x8 bf = *(const bf16x8*)(arow + kk * 16);
        acc = __builtin_amdgcn_mfma_f32_32x32x16_bf16(af, bf, acc, 0, 0, 0);
    }
#pragma unroll
    for (int rg = 0; rg < 4; rg++) {
        const int o0 = strip * 32 + rg * 8 + half * 4;
        f32x4 bv = *(const f32x4*)(bias + o0);
        uint2 w;
        w.x = pk2(acc[rg * 4 + 0] + bv[0], acc[rg * 4 + 1] + bv[1]);
        w.y = pk2(acc[rg * 4 + 2] + bv[2], acc[rg * 4 + 3] + bv[3]);
        *(uint2*)(dst + t * LSTRIDE + o0) = w;
    }
}

// conv3 (zero-pad) + sigmoid on 4 channels of row rr from bf16 buffer F.
__device__ inline void conv_sig4(const float* __restrict__ CW,
                                 const float* __restrict__ CB, int cb,
                                 const ushort_t* F, int rr, bool zl, bool zr,
                                 float out[4]) {
    uint2 m_ = *(const uint2*)(F + (rr - 1) * LSTRIDE + cb);
    uint2 c_ = *(const uint2*)(F + rr * LSTRIDE + cb);
    uint2 p_ = *(const uint2*)(F + (rr + 1) * LSTRIDE + cb);
    f32x4 w0 = *(const f32x4*)(CW + cb);
    f32x4 w1 = *(const f32x4*)(CW + 64 + cb);
    f32x4 w2 = *(const f32x4*)(CW + 128 + cb);
    f32x4 bb = *(const f32x4*)(CB + cb);
    float xm[4] = {lo2f(m_.x), hi2f(m_.x), lo2f(m_.y), hi2f(m_.y)};
    float x0[4] = {lo2f(c_.x), hi2f(c_.x), lo2f(c_.y), hi2f(c_.y)};
    float xp[4] = {lo2f(p_.x), hi2f(p_.x), lo2f(p_.y), hi2f(p_.y)};
#pragma unroll
    for (int i = 0; i < 4; i++) {
        float a = fmaf(w0[i], zl ? 0.f : xm[i],
                  fmaf(w1[i], x0[i],
                  fmaf(w2[i], zr ? 0.f : xp[i], bb[i])));
        out[i] = sigmoidf_(a);
    }
}

__global__ __launch_bounds__(512, 8) void gdn_kernel(
    const float* __restrict__ xg, const float* __restrict__ norm_g,
    const ushort_t* __restrict__ wpack,
    const float* __restrict__ qcw, const float* __restrict__ qcb,
    const float* __restrict__ kcw, const float* __restrict__ kcb,
    const float* __restrict__ vcw, const float* __restrict__ vcb,
    const float* __restrict__ qbf, const float* __restrict__ kbf,
    const float* __restrict__ vbf, const float* __restrict__ abf,
    const float* __restrict__ bbf, const float* __restrict__ pbf,
    const float* __restrict__ post_g,
    float* __restrict__ outg, int tiles_per_b) {
    __shared__ __align__(16) ushort_t Xs[ROWS * LSTRIDE];   // bf16 x rows t0-1..t0+32
    __shared__ __align__(16) ushort_t Hs[ROWS * LSTRIDE];   // h; rows 1..32 become Ns
    __shared__ __align__(16) ushort_t Fq[ROWS * LSTRIDE];   // qlin; later dhat
    __shared__ __align__(16) ushort_t Fk[ROWS * LSTRIDE];
    __shared__ __align__(16) ushort_t Fv[ROWS * LSTRIDE];
    __shared__ __align__(16) ushort_t Fa[ROWS * LSTRIDE];
    __shared__ __align__(16) ushort_t Fb[ROWS * LSTRIDE];
    __shared__ __align__(16) float CWs[768];
    // CWs: [0..191] q taps (tap-major [3][64]); [192..383] k; [384..575] v;
    //      [576] qcb; [640] kcb; [704] vcb

    const int tid    = threadIdx.x;
    const int wave   = tid >> 6;
    const int lane   = tid & 63;
    const int cb     = (tid & 15) * 4;   // channel base (4 ch/lane)
    const int rgrp   = tid >> 4;         // 0..31
    const int bidx = blockIdx.x;
    const int b    = bidx / tiles_per_b;
    const int tile = bidx % tiles_per_b;
    const int t0   = tile * TBS;
    const bool left_edge  = (t0 == 0);
    const bool right_edge = (t0 + TBS >= T_LEN);

    // ---- Stage A: x from global; zc_rmsnorm in-register; Xs+Hs bf16 --------
    {
        const f32x4 gv = *(const f32x4*)(norm_g + cb);
        for (int r = rgrp; r < ROWS; r += 32) {
            int t = t0 + r - 1;
            f32x4 xv = {0.f, 0.f, 0.f, 0.f};
            if (t >= 0 && t < T_LEN)
                xv = *(const f32x4*)(xg + ((size_t)b * T_LEN + t) * DD + cb);
            float s = (xv[0] + xv[1]) + (xv[2] + xv[3]);
            float mean = sum16(s) * (1.f / 64.f);
            f32x4 x0;
            float ms = 0.f;
#pragma unroll
            for (int i = 0; i < 4; i++) { x0[i] = xv[i] - mean; ms = fmaf(x0[i], x0[i], ms); }
            float inv = rsqrtf(sum16(ms) * (1.f / 64.f) + 1e-8f);
            uint2 xpk; xpk.x = pk2(xv[0], xv[1]); xpk.y = pk2(xv[2], xv[3]);
            *(uint2*)(Xs + r * LSTRIDE + cb) = xpk;
            uint2 hpk;
            hpk.x = pk2(x0[0] * inv * gv[0], x0[1] * inv * gv[1]);
            hpk.y = pk2(x0[2] * inv * gv[2], x0[3] * inv * gv[3]);
            *(uint2*)(Hs + r * LSTRIDE + cb) = hpk;
        }
    }
    // conv taps + biases -> CWs (tap-major)
    if (tid < 192) {
        int tap = tid >> 6, c = tid & 63;
        CWs[tid]       = qcw[c * 3 + tap];
        CWs[192 + tid] = kcw[c * 3 + tap];
        CWs[384 + tid] = vcw[c * 3 + tap];
    } else if (tid < 256) {
        int c = tid - 192;
        CWs[576 + c] = qcb[c];
        CWs[640 + c] = kcb[c];
        CWs[704 + c] = vcb[c];
    }
    __syncthreads();

    // ---- Stage B: six GEMMs as 16 strip-units, 2 per wave ------------------
    // u<12: g=u>>2 (q,k,v), m-half=(u>>1)&1 -> m0 {0,2}, strip=u&1, src=Hs
    // u>=12: g'=(u-12)>>1 (a,b), m0=1, strip=u&1, src=Xs
    // Overlapping m-halves write identical values (benign).
#pragma unroll
    for (int i = 0; i < 2; i++) {
        const int u = wave * 2 + i;
        const ushort_t* W; const float* bias; const ushort_t* src; ushort_t* dst;
        int m0, strip;
        if (u < 12) {
            const int g = u >> 2, sub = u & 3;
            W = wpack + g * 4096;
            bias = (g == 0) ? qbf : (g == 1) ? kbf : vbf;
            dst  = (g == 0) ? Fq  : (g == 1) ? Fk  : Fv;
            src = Hs;
            m0 = (sub & 2) ? 2 : 0;
            strip = sub & 1;
        } else {
            const int g = (u - 12) >> 1;
            W = wpack + (3 + g) * 4096;
            bias = g ? bbf : abf;
            dst  = g ? Fb  : Fa;
            src = Xs;
            m0 = 1;
            strip = u & 1;
        }
        mm32(W, bias, src, dst, m0, strip, lane);
    }
    __syncthreads();

    // ---- Stage C: conv+sig (q,k,v), l2norm(q,k), delta, gate, post-norm ----
    {
        const int rr = rgrp + 1;                // 1..32
        const bool zl = (rr == 1) && left_edge;
        const bool zr = (rr == TBS) && right_edge;
        float qs[4], ks[4], vs[4];
        conv_sig4(CWs,       CWs + 576, cb, Fq, rr, zl, zr, qs);
        conv_sig4(CWs + 192, CWs + 640, cb, Fk, rr, zl, zr, ks);
        conv_sig4(CWs + 384, CWs + 704, cb, Fv, rr, zl, zr, vs);
        float sq = 0.f, sk = 0.f;
#pragma unroll
        for (int i = 0; i < 4; i++) {
            sq = fmaf(qs[i], qs[i], sq);
            sk = fmaf(ks[i], ks[i], sk);
        }
        float qi = rsqrtf(sum16(sq) + 1e-8f);
        float ki = rsqrtf(sum16(sk) + 1e-8f);
        uint2 av = *(const uint2*)(Fa + rr * LSTRIDE + cb);
        uint2 bv = *(const uint2*)(Fb + rr * LSTRIDE + cb);
        float af[4] = {lo2f(av.x), hi2f(av.x), lo2f(av.y), hi2f(av.y)};
        float bf[4] = {lo2f(bv.x), hi2f(bv.x), lo2f(bv.y), hi2f(bv.y)};
        float d2[4]; float sm = 0.f;
#pragma unroll
        for (int i = 0; i < 4; i++) {
            float delta = (qs[i] * qi) * (ks[i] * ki) * vs[i];
            d2[i] = fmaf(tanhf_(af[i]), delta, bf[i]);
            sm += d2[i];
        }
        float mean = sum16(sm) * (1.f / 64.f);
        float ms = 0.f;
#pragma unroll
        for (int i = 0; i < 4; i++) { d2[i] -= mean; ms = fmaf(d2[i], d2[i], ms); }
        float inv = rsqrtf(sum16(ms) * (1.f / 64.f) + 1e-8f);
        const f32x4 pgv = *(const f32x4*)(post_g + cb);
        uint2 npk;
        npk.x = pk2(d2[0] * inv * pgv[0], d2[1] * inv * pgv[1]);
        npk.y = pk2(d2[2] * inv * pgv[2], d2[3] * inv * pgv[3]);
        *(uint2*)(Hs + rr * LSTRIDE + cb) = npk;   // Ns into Hs rows 1..32
    }
    __syncthreads();

    // ---- Stage D: dhat = Ns @ pw^T + pb (2 strips on waves 0,1) ------------
    if (wave < 2)
        mm32(wpack + 5 * 4096, pbf, Hs, Fq, 1, wave, lane);
    __syncthreads();

    // ---- Stage E: out = x + sigmoid(silu(dhat))*dhat -----------------------
    {
        const int rr = rgrp + 1;                // 1..32
        const int t = t0 + rgrp;
        uint2 dpk = *(const uint2*)(Fq + rr * LSTRIDE + cb);
        float dh[4] = {lo2f(dpk.x), hi2f(dpk.x), lo2f(dpk.y), hi2f(dpk.y)};
        const float* xrow = xg + ((size_t)b * T_LEN + t) * DD + cb;
        f32x4 xv = *(const f32x4*)(xrow);
        f32x4 ov;
#pragma unroll
        for (int i = 0; i < 4; i++) {
            float sl = dh[i] * sigmoidf_(dh[i]);
            ov[i] = xv[i] + sigmoidf_(sl) * dh[i];
        }
        *(f32x4*)(outg + ((size_t)b * T_LEN + t) * DD + cb) = ov;
    }
}

extern "C" void kernel_launch(void* const* d_in, const int* in_sizes, int n_in,
                              void* d_out, int out_size, void* d_ws, size_t ws_size,
                              hipStream_t stream) {
    const float* xg     = (const float*)d_in[0];
    const float* norm_g = (const float*)d_in[1];
    const float* qw  = (const float*)d_in[2];
    const float* qb  = (const float*)d_in[3];
    const float* kw  = (const float*)d_in[4];
    const float* kb  = (const float*)d_in[5];
    const float* vw  = (const float*)d_in[6];
    const float* vb  = (const float*)d_in[7];
    const float* qcw = (const float*)d_in[8];
    const float* qcb = (const float*)d_in[9];
    const float* kcw = (const float*)d_in[10];
    const float* kcb = (const float*)d_in[11];
    const float* vcw = (const float*)d_in[12];
    const float* vcb = (const float*)d_in[13];
    const float* aw  = (const float*)d_in[14];
    const float* ab  = (const float*)d_in[15];
    const float* bw  = (const float*)d_in[16];
    const float* bb  = (const float*)d_in[17];
    const float* pg  = (const float*)d_in[18];
    const float* pw  = (const float*)d_in[19];
    const float* pb  = (const float*)d_in[20];

    ushort_t* wpack = (ushort_t*)d_ws;

    hipLaunchKernelGGL(cvt_kernel, dim3(96), dim3(256), 0, stream,
                       qw, kw, vw, aw, bw, pw, wpack);

    const int B = in_sizes[0] / (T_LEN * DD);
    const int tiles_per_b = T_LEN / TBS;    // 128
    hipLaunchKernelGGL(gdn_kernel, dim3(B * tiles_per_b), dim3(512), 0, stream,
                       xg, norm_g, wpack, qcw, qcb, kcw, kcb, vcw, vcb,
                       qb, kb, vb, ab, bb, pb, pg,
                       (float*)d_out, tiles_per_b);
}